// Round 5
// baseline (1176.842 us; speedup 1.0000x reference)
//
#include <hip/hip_runtime.h>

#define NN 50000
#define EE 800000
#define FIN 16
#define EDIM 4
#define EMB 32
#define NH 4
#define HC 128          // EMB*NH
#define NL 2
#define DENSE 128

// ---------------- CSR build ----------------
__global__ void hist_kernel(const int* __restrict__ dst, int* __restrict__ counts) {
    int e = blockIdx.x * blockDim.x + threadIdx.x;
    if (e < EE) atomicAdd(&counts[dst[e]], 1);
}

__global__ __launch_bounds__(1024) void scan_kernel(int* __restrict__ cursor, int* __restrict__ row_ptr) {
    __shared__ int wsum[16];
    __shared__ int carry_s;
    int tid = threadIdx.x;
    int lane = tid & 63, wid = tid >> 6;
    int base = 0;
    const int nchunk = (NN + 1023) / 1024;
    for (int ch = 0; ch < nchunk; ++ch) {
        int i = ch * 1024 + tid;
        int v = (i < NN) ? cursor[i] : 0;
        int incl = v;
        #pragma unroll
        for (int off = 1; off < 64; off <<= 1) {
            int t = __shfl_up(incl, off, 64);
            if (lane >= off) incl += t;
        }
        if (lane == 63) wsum[wid] = incl;
        __syncthreads();
        if (tid == 0) {
            int s = 0;
            #pragma unroll
            for (int w = 0; w < 16; ++w) { int t = wsum[w]; wsum[w] = s; s += t; }
            carry_s = s;
        }
        __syncthreads();
        int excl = base + wsum[wid] + incl - v;
        if (i < NN) { row_ptr[i] = excl; cursor[i] = excl; }
        base += carry_s;
        __syncthreads();   // protect wsum/carry_s before next chunk
    }
    if (tid == 0) row_ptr[NN] = base;
}

__global__ void scatter_kernel(const int* __restrict__ src, const int* __restrict__ dst,
                               const float* __restrict__ ea, int* __restrict__ cursor,
                               int* __restrict__ ssrc, float4* __restrict__ sea) {
    int e = blockIdx.x * blockDim.x + threadIdx.x;
    if (e >= EE) return;
    int d = dst[e];
    int pos = atomicAdd(&cursor[d], 1);
    ssrc[pos] = src[e];
    sea[pos] = *reinterpret_cast<const float4*>(ea + (size_t)e * 4);
}

// ---------------- node projections: Q,K,V + skip(into Out) ----------------
template<int F>
__global__ __launch_bounds__(512) void qkvs_kernel(const float* __restrict__ hin,
        const float* __restrict__ Wq, const float* __restrict__ bq,
        const float* __restrict__ Wk, const float* __restrict__ bk,
        const float* __restrict__ Wv, const float* __restrict__ bv,
        const float* __restrict__ Ws, const float* __restrict__ bs,
        float* __restrict__ Q, float* __restrict__ K, float* __restrict__ V,
        float* __restrict__ Out) {
    __shared__ float hrow[F];
    int n = blockIdx.x;
    if (threadIdx.x < F) hrow[threadIdx.x] = hin[(size_t)n * F + threadIdx.x];
    __syncthreads();
    int m = threadIdx.x >> 7, c = threadIdx.x & 127;
    const float* W; const float* b; float* O;
    switch (m) {
        case 0:  W = Wq; b = bq; O = Q;   break;
        case 1:  W = Wk; b = bk; O = K;   break;
        case 2:  W = Wv; b = bv; O = V;   break;
        default: W = Ws; b = bs; O = Out; break;
    }
    float s = b[c];
    #pragma unroll
    for (int f = 0; f < F; ++f) s += hrow[f] * W[f * HC + c];
    O[(size_t)n * HC + c] = s;
}

// ---------------- edge attention (one wave per dst node) ----------------
__global__ __launch_bounds__(256) void edge_attn_kernel(const int* __restrict__ row_ptr,
        const int* __restrict__ ssrc, const float4* __restrict__ sea,
        const float* __restrict__ We,
        const float* __restrict__ Q, const float* __restrict__ K, const float* __restrict__ V,
        float* __restrict__ Out) {
    int n = blockIdx.x * 4 + (threadIdx.x >> 6);   // grid*4 == NN exactly
    int lane = threadIdx.x & 63;
    int c0 = lane, c1 = lane + 64;
    float we0[4], we1[4];
    #pragma unroll
    for (int d = 0; d < 4; ++d) { we0[d] = We[d * HC + c0]; we1[d] = We[d * HC + c1]; }
    float q0 = Q[(size_t)n * HC + c0], q1 = Q[(size_t)n * HC + c1];
    int start = row_ptr[n], end = row_ptr[n + 1];
    float m0 = -INFINITY, z0 = 0.f, a0 = 0.f;
    float m1 = -INFINITY, z1 = 0.f, a1 = 0.f;
    const float SC = 0.17677669529663687f;  // 1/sqrt(32)
    for (int i = start; i < end; ++i) {
        int s = ssrc[i];
        s = s < 0 ? 0 : (s >= NN ? NN - 1 : s);           // insurance clamp
        float4 ea = sea[i];
        float e0 = ea.x * we0[0] + ea.y * we0[1] + ea.z * we0[2] + ea.w * we0[3];
        float e1 = ea.x * we1[0] + ea.y * we1[1] + ea.z * we1[2] + ea.w * we1[3];
        const float* Kr = K + (size_t)s * HC;
        const float* Vr = V + (size_t)s * HC;
        float p0 = q0 * (Kr[c0] + e0);
        float p1 = q1 * (Kr[c1] + e1);
        // per-head (32-channel) butterfly sums: xor offsets 1..16 stay within 32-lane groups
        #pragma unroll
        for (int off = 1; off < 32; off <<= 1) {
            p0 += __shfl_xor(p0, off, 64);
            p1 += __shfl_xor(p1, off, 64);
        }
        float l0 = p0 * SC, l1 = p1 * SC;
        float nm0 = fmaxf(m0, l0), nm1 = fmaxf(m1, l1);
        float sc0 = __expf(m0 - nm0), sc1 = __expf(m1 - nm1);  // expf(-inf)=0 first iter
        float pe0 = __expf(l0 - nm0), pe1 = __expf(l1 - nm1);
        float v0 = Vr[c0] + e0, v1 = Vr[c1] + e1;
        a0 = a0 * sc0 + pe0 * v0;  z0 = z0 * sc0 + pe0;  m0 = nm0;
        a1 = a1 * sc1 + pe1 * v1;  z1 = z1 * sc1 + pe1;  m1 = nm1;
    }
    Out[(size_t)n * HC + c0] += a0 / (z0 + 1e-16f);
    Out[(size_t)n * HC + c1] += a1 / (z1 + 1e-16f);
}

// ---------------- h = relu(Out @ Wt + bt) ----------------
__global__ void transform_kernel(const float* __restrict__ Out, const float* __restrict__ Wt,
                                 const float* __restrict__ bt, float* __restrict__ h) {
    int idx = blockIdx.x * blockDim.x + threadIdx.x;
    if (idx >= NN * EMB) return;
    int n = idx >> 5, c = idx & 31;
    const float* r = Out + (size_t)n * HC;
    float s = bt[c];
    #pragma unroll 8
    for (int j = 0; j < HC; ++j) s += r[j] * Wt[j * EMB + c];
    h[idx] = fmaxf(s, 0.f);
}

// ---------------- fused dense head (wave per node), FLOAT32 output ----------------
__global__ __launch_bounds__(256) void head_kernel(const float* __restrict__ h,
        const float* __restrict__ W1, const float* __restrict__ b1,
        const float* __restrict__ W2, const float* __restrict__ b2,
        const float* __restrict__ W3, const float* __restrict__ b3,
        float* __restrict__ out) {
    __shared__ float sh[4][EMB];
    __shared__ float sd1[4][DENSE];
    int wid = threadIdx.x >> 6, lane = threadIdx.x & 63;
    int n = blockIdx.x * 4 + wid;           // NN % 4 == 0
    if (lane < EMB) sh[wid][lane] = h[(size_t)n * EMB + lane];
    __syncthreads();
    float s0 = b1[lane], s1 = b1[lane + 64];
    #pragma unroll
    for (int f = 0; f < EMB; ++f) {
        float hv = sh[wid][f];
        s0 += hv * W1[f * DENSE + lane];
        s1 += hv * W1[f * DENSE + lane + 64];
    }
    sd1[wid][lane] = fmaxf(s0, 0.f);
    sd1[wid][lane + 64] = fmaxf(s1, 0.f);
    __syncthreads();
    float s2 = b2[lane];
    #pragma unroll 8
    for (int j = 0; j < DENSE; ++j) s2 += sd1[wid][j] * W2[j * 64 + lane];
    s2 = fmaxf(s2, 0.f);
    float t = s2 * W3[lane];
    #pragma unroll
    for (int off = 1; off < 64; off <<= 1) t += __shfl_xor(t, off, 64);
    if (lane == 0) {
        float x = t + b3[0];
        out[n] = 1.f / (1.f + __expf(-x));   // f32 store — the round-5 fix
    }
}

extern "C" void kernel_launch(void* const* d_in, const int* in_sizes, int n_in,
                              void* d_out, int out_size, void* d_ws, size_t ws_size,
                              hipStream_t stream) {
    const float* x   = (const float*)d_in[0];
    const int*   ei  = (const int*)d_in[1];    // [2,E]: src=ei, dst=ei+E
    const float* ea  = (const float*)d_in[2];
    const float* Wq0 = (const float*)d_in[3];  const float* bq0 = (const float*)d_in[4];
    const float* Wk0 = (const float*)d_in[5];  const float* bk0 = (const float*)d_in[6];
    const float* Wv0 = (const float*)d_in[7];  const float* bv0 = (const float*)d_in[8];
    const float* We0 = (const float*)d_in[9];
    const float* Ws0 = (const float*)d_in[10]; const float* bs0 = (const float*)d_in[11];
    const float* Wt0 = (const float*)d_in[12]; const float* bt0 = (const float*)d_in[13];
    const float* WqL = (const float*)d_in[14]; const float* bqL = (const float*)d_in[15];
    const float* WkL = (const float*)d_in[16]; const float* bkL = (const float*)d_in[17];
    const float* WvL = (const float*)d_in[18]; const float* bvL = (const float*)d_in[19];
    const float* WeL = (const float*)d_in[20];
    const float* WsL = (const float*)d_in[21]; const float* bsL = (const float*)d_in[22];
    const float* WtL = (const float*)d_in[23]; const float* btL = (const float*)d_in[24];
    const float* W1  = (const float*)d_in[25]; const float* b1  = (const float*)d_in[26];
    const float* W2  = (const float*)d_in[27]; const float* b2  = (const float*)d_in[28];
    const float* W3  = (const float*)d_in[29]; const float* b3  = (const float*)d_in[30];
    float* out = (float*)d_out;               // reference returns float32

    char* ws = (char*)d_ws;
    size_t off = 0;
    auto alloc = [&](size_t bytes) -> void* {
        void* p = ws + off; off = (off + bytes + 255) & ~(size_t)255; return p;
    };
    int*    cursor  = (int*)   alloc((size_t)NN * 4);
    int*    row_ptr = (int*)   alloc((size_t)(NN + 1) * 4);
    int*    ssrc    = (int*)   alloc((size_t)EE * 4);
    float4* sea     = (float4*)alloc((size_t)EE * 16);
    float*  hbuf    = (float*) alloc((size_t)NN * EMB * 4);
    float*  Q       = (float*) alloc((size_t)NN * HC * 4);
    float*  K       = (float*) alloc((size_t)NN * HC * 4);
    float*  V       = (float*) alloc((size_t)NN * HC * 4);
    float*  Outb    = (float*) alloc((size_t)NN * HC * 4);
    // total ~125 MB

    // ---- CSR by dst (edge_index shared by all 3 conv layers) ----
    hipMemsetAsync(cursor, 0, (size_t)NN * 4, stream);
    hist_kernel<<<(EE + 255) / 256, 256, 0, stream>>>(ei + EE, cursor);
    scan_kernel<<<1, 1024, 0, stream>>>(cursor, row_ptr);
    scatter_kernel<<<(EE + 255) / 256, 256, 0, stream>>>(ei, ei + EE, ea, cursor, ssrc, sea);

    // ---- layer 0 (F_IN=16, f32 input x) ----
    qkvs_kernel<FIN><<<NN, 512, 0, stream>>>(x, Wq0, bq0, Wk0, bk0, Wv0, bv0, Ws0, bs0,
                                             Q, K, V, Outb);
    edge_attn_kernel<<<NN / 4, 256, 0, stream>>>(row_ptr, ssrc, sea, We0, Q, K, V, Outb);
    transform_kernel<<<(NN * EMB + 255) / 256, 256, 0, stream>>>(Outb, Wt0, bt0, hbuf);

    // ---- inner layers (F=EMB=32) ----
    for (int l = 0; l < NL; ++l) {
        qkvs_kernel<EMB><<<NN, 512, 0, stream>>>(hbuf,
            WqL + l * EMB * HC, bqL + l * HC,
            WkL + l * EMB * HC, bkL + l * HC,
            WvL + l * EMB * HC, bvL + l * HC,
            WsL + l * EMB * HC, bsL + l * HC,
            Q, K, V, Outb);
        edge_attn_kernel<<<NN / 4, 256, 0, stream>>>(row_ptr, ssrc, sea,
            WeL + l * EDIM * HC, Q, K, V, Outb);
        transform_kernel<<<(NN * EMB + 255) / 256, 256, 0, stream>>>(Outb,
            WtL + l * HC * EMB, btL + l * EMB, hbuf);
    }

    // ---- dense head ----
    head_kernel<<<NN / 4, 256, 0, stream>>>(hbuf, W1, b1, W2, b2, W3, b3, out);
}

// Round 6
// 914.697 us; speedup vs baseline: 1.2866x; 1.2866x over previous
//
#include <hip/hip_runtime.h>

#define NN 50000
#define EE 800000
#define FIN 16
#define EDIM 4
#define EMB 32
#define NH 4
#define HC 128          // EMB*NH
#define NL 2
#define DENSE 128
#define QNPB 50         // nodes per qkvs block (50000 = 1000 * 50)

// unpack two packed fp16 -> float2
__device__ __forceinline__ float2 h2f2(unsigned int u) {
    union { unsigned int u; _Float16 h[2]; } c; c.u = u;
    return make_float2((float)c.h[0], (float)c.h[1]);
}

// ---------------- CSR build ----------------
__global__ void hist_kernel(const int* __restrict__ dst, int* __restrict__ counts) {
    int e = blockIdx.x * blockDim.x + threadIdx.x;
    if (e < EE) atomicAdd(&counts[dst[e]], 1);
}

// two-phase parallel scan: thread t owns a contiguous chunk of ~49 elements
__global__ __launch_bounds__(1024) void scan_kernel(int* __restrict__ cursor, int* __restrict__ row_ptr) {
    const int PER = (NN + 1023) / 1024;   // 49
    __shared__ int wsum[16];
    __shared__ int wpre[17];
    int tid = threadIdx.x, lane = tid & 63, wid = tid >> 6;
    int base = tid * PER;
    // phase 1: per-thread chunk sum
    int s = 0;
    for (int j = 0; j < PER; ++j) {
        int i = base + j;
        if (i < NN) s += cursor[i];
    }
    // wave-inclusive scan of chunk sums
    int incl = s;
    #pragma unroll
    for (int off = 1; off < 64; off <<= 1) {
        int t = __shfl_up(incl, off, 64);
        if (lane >= off) incl += t;
    }
    if (lane == 63) wsum[wid] = incl;
    __syncthreads();
    if (tid == 0) {
        int acc = 0;
        #pragma unroll
        for (int w = 0; w < 16; ++w) { wpre[w] = acc; acc += wsum[w]; }
        wpre[16] = acc;
    }
    __syncthreads();
    int run = wpre[wid] + incl - s;       // exclusive prefix of this thread's chunk
    // phase 2: per-element exclusive prefix
    for (int j = 0; j < PER; ++j) {
        int i = base + j;
        if (i < NN) {
            int v = cursor[i];
            row_ptr[i] = run;
            cursor[i] = run;
            run += v;
        }
    }
    if (tid == 0) row_ptr[NN] = wpre[16];
}

__global__ void scatter_kernel(const int* __restrict__ src, const int* __restrict__ dst,
                               const float* __restrict__ ea, int* __restrict__ cursor,
                               int* __restrict__ ssrc, unsigned long long* __restrict__ sea) {
    int e = blockIdx.x * blockDim.x + threadIdx.x;
    if (e >= EE) return;
    int d = dst[e];
    int pos = atomicAdd(&cursor[d], 1);
    ssrc[pos] = src[e];
    float4 q = *reinterpret_cast<const float4*>(ea + (size_t)e * 4);
    union { unsigned long long u; _Float16 h[4]; } pk;
    pk.h[0] = (_Float16)q.x; pk.h[1] = (_Float16)q.y;
    pk.h[2] = (_Float16)q.z; pk.h[3] = (_Float16)q.w;
    sea[pos] = pk.u;
}

// ---------------- node projections: Q f32, K/V packed fp16, skip f32 into Out ----------
// Weights live in REGISTERS (F per thread), looped over QNPB nodes per block.
template<int F>
__global__ __launch_bounds__(512) void qkvs_kernel(const float* __restrict__ hin,
        const float* __restrict__ Wq, const float* __restrict__ bq,
        const float* __restrict__ Wk, const float* __restrict__ bk,
        const float* __restrict__ Wv, const float* __restrict__ bv,
        const float* __restrict__ Ws, const float* __restrict__ bs,
        float* __restrict__ Q, _Float16* __restrict__ kvh,
        float* __restrict__ Out) {
    __shared__ float hs[QNPB][F];
    int tid = threadIdx.x;
    int m = tid >> 7, c = tid & 127;
    const float* W; const float* b;
    switch (m) {
        case 0:  W = Wq; b = bq; break;
        case 1:  W = Wk; b = bk; break;
        case 2:  W = Wv; b = bv; break;
        default: W = Ws; b = bs; break;
    }
    float w[F];
    #pragma unroll
    for (int f = 0; f < F; ++f) w[f] = W[f * HC + c];   // column c, coalesced per group
    float bias = b[c];

    int node0 = blockIdx.x * QNPB;
    // stage QNPB node rows (contiguous, coalesced)
    for (int i = tid; i < QNPB * F; i += 512)
        hs[i / F][i % F] = hin[(size_t)node0 * F + i];
    __syncthreads();

    for (int k = 0; k < QNPB; ++k) {
        float s = bias;
        #pragma unroll
        for (int f = 0; f < F; ++f) s += hs[k][f] * w[f];   // LDS broadcast
        size_t n = node0 + k;
        if      (m == 0) Q[n * HC + c] = s;
        else if (m == 1) kvh[n * 256 + 2 * c] = (_Float16)s;       // K -> low half
        else if (m == 2) kvh[n * 256 + 2 * c + 1] = (_Float16)s;   // V -> high half
        else             Out[n * HC + c] = s;
    }
}

// ---------------- edge attention (one wave per dst node), fp16 KV gather ----------------
__global__ __launch_bounds__(256) void edge_attn_kernel(const int* __restrict__ row_ptr,
        const int* __restrict__ ssrc, const unsigned long long* __restrict__ sea,
        const float* __restrict__ We,
        const float* __restrict__ Q, const unsigned int* __restrict__ kv,
        float* __restrict__ Out) {
    int n = blockIdx.x * 4 + (threadIdx.x >> 6);   // grid*4 == NN exactly
    int lane = threadIdx.x & 63;
    int c0 = lane, c1 = lane + 64;
    float we0[4], we1[4];
    #pragma unroll
    for (int d = 0; d < 4; ++d) { we0[d] = We[d * HC + c0]; we1[d] = We[d * HC + c1]; }
    float q0 = Q[(size_t)n * HC + c0], q1 = Q[(size_t)n * HC + c1];
    int start = row_ptr[n], end = row_ptr[n + 1];
    float m0 = -INFINITY, z0 = 0.f, a0 = 0.f;
    float m1 = -INFINITY, z1 = 0.f, a1 = 0.f;
    const float SC = 0.17677669529663687f;  // 1/sqrt(32)
    int i = start;
    // 2 edges per iteration: independent gather+butterfly chains for ILP
    for (; i + 1 < end; i += 2) {
        int sA = ssrc[i], sB = ssrc[i + 1];
        sA = sA < 0 ? 0 : (sA >= NN ? NN - 1 : sA);
        sB = sB < 0 ? 0 : (sB >= NN ? NN - 1 : sB);
        unsigned long long epA = sea[i], epB = sea[i + 1];
        unsigned int kvA0 = kv[(size_t)sA * 128 + c0], kvA1 = kv[(size_t)sA * 128 + c1];
        unsigned int kvB0 = kv[(size_t)sB * 128 + c0], kvB1 = kv[(size_t)sB * 128 + c1];
        float2 eaA01 = h2f2((unsigned int)epA), eaA23 = h2f2((unsigned int)(epA >> 32));
        float2 eaB01 = h2f2((unsigned int)epB), eaB23 = h2f2((unsigned int)(epB >> 32));
        float eA0 = eaA01.x * we0[0] + eaA01.y * we0[1] + eaA23.x * we0[2] + eaA23.y * we0[3];
        float eA1 = eaA01.x * we1[0] + eaA01.y * we1[1] + eaA23.x * we1[2] + eaA23.y * we1[3];
        float eB0 = eaB01.x * we0[0] + eaB01.y * we0[1] + eaB23.x * we0[2] + eaB23.y * we0[3];
        float eB1 = eaB01.x * we1[0] + eaB01.y * we1[1] + eaB23.x * we1[2] + eaB23.y * we1[3];
        float2 kA0 = h2f2(kvA0), kA1 = h2f2(kvA1);
        float2 kB0 = h2f2(kvB0), kB1 = h2f2(kvB1);
        float pA0 = q0 * (kA0.x + eA0), pA1 = q1 * (kA1.x + eA1);
        float pB0 = q0 * (kB0.x + eB0), pB1 = q1 * (kB1.x + eB1);
        #pragma unroll
        for (int off = 1; off < 32; off <<= 1) {
            pA0 += __shfl_xor(pA0, off, 64);
            pA1 += __shfl_xor(pA1, off, 64);
            pB0 += __shfl_xor(pB0, off, 64);
            pB1 += __shfl_xor(pB1, off, 64);
        }
        float lA0 = pA0 * SC, lA1 = pA1 * SC, lB0 = pB0 * SC, lB1 = pB1 * SC;
        float vA0 = kA0.y + eA0, vA1 = kA1.y + eA1;
        float vB0 = kB0.y + eB0, vB1 = kB1.y + eB1;
        // joint online-softmax update for both edges
        float nm0 = fmaxf(m0, fmaxf(lA0, lB0));
        float nm1 = fmaxf(m1, fmaxf(lA1, lB1));
        float sc0 = __expf(m0 - nm0), xA0 = __expf(lA0 - nm0), xB0 = __expf(lB0 - nm0);
        float sc1 = __expf(m1 - nm1), xA1 = __expf(lA1 - nm1), xB1 = __expf(lB1 - nm1);
        a0 = a0 * sc0 + xA0 * vA0 + xB0 * vB0;  z0 = z0 * sc0 + xA0 + xB0;  m0 = nm0;
        a1 = a1 * sc1 + xA1 * vA1 + xB1 * vB1;  z1 = z1 * sc1 + xA1 + xB1;  m1 = nm1;
    }
    if (i < end) {
        int s = ssrc[i];
        s = s < 0 ? 0 : (s >= NN ? NN - 1 : s);
        unsigned long long ep = sea[i];
        unsigned int kv0 = kv[(size_t)s * 128 + c0], kv1 = kv[(size_t)s * 128 + c1];
        float2 ea01 = h2f2((unsigned int)ep), ea23 = h2f2((unsigned int)(ep >> 32));
        float e0 = ea01.x * we0[0] + ea01.y * we0[1] + ea23.x * we0[2] + ea23.y * we0[3];
        float e1 = ea01.x * we1[0] + ea01.y * we1[1] + ea23.x * we1[2] + ea23.y * we1[3];
        float2 k0 = h2f2(kv0), k1 = h2f2(kv1);
        float p0 = q0 * (k0.x + e0), p1 = q1 * (k1.x + e1);
        #pragma unroll
        for (int off = 1; off < 32; off <<= 1) {
            p0 += __shfl_xor(p0, off, 64);
            p1 += __shfl_xor(p1, off, 64);
        }
        float l0 = p0 * SC, l1 = p1 * SC;
        float nm0 = fmaxf(m0, l0), nm1 = fmaxf(m1, l1);
        float sc0 = __expf(m0 - nm0), x0 = __expf(l0 - nm0);
        float sc1 = __expf(m1 - nm1), x1 = __expf(l1 - nm1);
        a0 = a0 * sc0 + x0 * (k0.y + e0);  z0 = z0 * sc0 + x0;  m0 = nm0;
        a1 = a1 * sc1 + x1 * (k1.y + e1);  z1 = z1 * sc1 + x1;  m1 = nm1;
    }
    Out[(size_t)n * HC + c0] += a0 / (z0 + 1e-16f);
    Out[(size_t)n * HC + c1] += a1 / (z1 + 1e-16f);
}

// ---------------- h = relu(Out @ Wt + bt), float4 row loads ----------------
__global__ void transform_kernel(const float* __restrict__ Out, const float* __restrict__ Wt,
                                 const float* __restrict__ bt, float* __restrict__ h) {
    int idx = blockIdx.x * blockDim.x + threadIdx.x;
    if (idx >= NN * EMB) return;
    int n = idx >> 5, c = idx & 31;
    const float4* r4 = (const float4*)(Out + (size_t)n * HC);
    float s = bt[c];
    #pragma unroll 8
    for (int j = 0; j < 32; ++j) {
        float4 rv = r4[j];
        const float* wp = Wt + (4 * j) * EMB + c;
        s += rv.x * wp[0] + rv.y * wp[EMB] + rv.z * wp[2 * EMB] + rv.w * wp[3 * EMB];
    }
    h[idx] = fmaxf(s, 0.f);
}

// ---------------- fused dense head (wave per node), f32 output ----------------
__global__ __launch_bounds__(256) void head_kernel(const float* __restrict__ h,
        const float* __restrict__ W1, const float* __restrict__ b1,
        const float* __restrict__ W2, const float* __restrict__ b2,
        const float* __restrict__ W3, const float* __restrict__ b3,
        float* __restrict__ out) {
    __shared__ float sh[4][EMB];
    __shared__ float sd1[4][DENSE];
    int wid = threadIdx.x >> 6, lane = threadIdx.x & 63;
    int n = blockIdx.x * 4 + wid;           // NN % 4 == 0
    if (lane < EMB) sh[wid][lane] = h[(size_t)n * EMB + lane];
    __syncthreads();
    float s0 = b1[lane], s1 = b1[lane + 64];
    #pragma unroll
    for (int f = 0; f < EMB; ++f) {
        float hv = sh[wid][f];
        s0 += hv * W1[f * DENSE + lane];
        s1 += hv * W1[f * DENSE + lane + 64];
    }
    sd1[wid][lane] = fmaxf(s0, 0.f);
    sd1[wid][lane + 64] = fmaxf(s1, 0.f);
    __syncthreads();
    float s2 = b2[lane];
    #pragma unroll 8
    for (int j = 0; j < DENSE; ++j) s2 += sd1[wid][j] * W2[j * 64 + lane];
    s2 = fmaxf(s2, 0.f);
    float t = s2 * W3[lane];
    #pragma unroll
    for (int off = 1; off < 64; off <<= 1) t += __shfl_xor(t, off, 64);
    if (lane == 0) {
        float x = t + b3[0];
        out[n] = 1.f / (1.f + __expf(-x));
    }
}

extern "C" void kernel_launch(void* const* d_in, const int* in_sizes, int n_in,
                              void* d_out, int out_size, void* d_ws, size_t ws_size,
                              hipStream_t stream) {
    const float* x   = (const float*)d_in[0];
    const int*   ei  = (const int*)d_in[1];    // [2,E]: src=ei, dst=ei+E
    const float* ea  = (const float*)d_in[2];
    const float* Wq0 = (const float*)d_in[3];  const float* bq0 = (const float*)d_in[4];
    const float* Wk0 = (const float*)d_in[5];  const float* bk0 = (const float*)d_in[6];
    const float* Wv0 = (const float*)d_in[7];  const float* bv0 = (const float*)d_in[8];
    const float* We0 = (const float*)d_in[9];
    const float* Ws0 = (const float*)d_in[10]; const float* bs0 = (const float*)d_in[11];
    const float* Wt0 = (const float*)d_in[12]; const float* bt0 = (const float*)d_in[13];
    const float* WqL = (const float*)d_in[14]; const float* bqL = (const float*)d_in[15];
    const float* WkL = (const float*)d_in[16]; const float* bkL = (const float*)d_in[17];
    const float* WvL = (const float*)d_in[18]; const float* bvL = (const float*)d_in[19];
    const float* WeL = (const float*)d_in[20];
    const float* WsL = (const float*)d_in[21]; const float* bsL = (const float*)d_in[22];
    const float* WtL = (const float*)d_in[23]; const float* btL = (const float*)d_in[24];
    const float* W1  = (const float*)d_in[25]; const float* b1  = (const float*)d_in[26];
    const float* W2  = (const float*)d_in[27]; const float* b2  = (const float*)d_in[28];
    const float* W3  = (const float*)d_in[29]; const float* b3  = (const float*)d_in[30];
    float* out = (float*)d_out;

    char* ws = (char*)d_ws;
    size_t off = 0;
    auto alloc = [&](size_t bytes) -> void* {
        void* p = ws + off; off = (off + bytes + 255) & ~(size_t)255; return p;
    };
    int*     cursor  = (int*)    alloc((size_t)NN * 4);
    int*     row_ptr = (int*)    alloc((size_t)(NN + 1) * 4);
    int*     ssrc    = (int*)    alloc((size_t)EE * 4);
    unsigned long long* sea = (unsigned long long*)alloc((size_t)EE * 8);
    float*   hbuf    = (float*)  alloc((size_t)NN * EMB * 4);
    float*   Q       = (float*)  alloc((size_t)NN * HC * 4);
    _Float16* kvh    = (_Float16*)alloc((size_t)NN * HC * 2 * 2);  // packed (k,v) per channel
    float*   Outb    = (float*)  alloc((size_t)NN * HC * 4);
    // total ~93 MB

    // ---- CSR by dst (edge_index shared by all 3 conv layers) ----
    hipMemsetAsync(cursor, 0, (size_t)NN * 4, stream);
    hist_kernel<<<(EE + 255) / 256, 256, 0, stream>>>(ei + EE, cursor);
    scan_kernel<<<1, 1024, 0, stream>>>(cursor, row_ptr);
    scatter_kernel<<<(EE + 255) / 256, 256, 0, stream>>>(ei, ei + EE, ea, cursor, ssrc, sea);

    const unsigned int* kvu = (const unsigned int*)kvh;

    // ---- layer 0 (F_IN=16) ----
    qkvs_kernel<FIN><<<NN / QNPB, 512, 0, stream>>>(x, Wq0, bq0, Wk0, bk0, Wv0, bv0,
                                                    Ws0, bs0, Q, kvh, Outb);
    edge_attn_kernel<<<NN / 4, 256, 0, stream>>>(row_ptr, ssrc, sea, We0, Q, kvu, Outb);
    transform_kernel<<<(NN * EMB + 255) / 256, 256, 0, stream>>>(Outb, Wt0, bt0, hbuf);

    // ---- inner layers (F=EMB=32) ----
    for (int l = 0; l < NL; ++l) {
        qkvs_kernel<EMB><<<NN / QNPB, 512, 0, stream>>>(hbuf,
            WqL + l * EMB * HC, bqL + l * HC,
            WkL + l * EMB * HC, bkL + l * HC,
            WvL + l * EMB * HC, bvL + l * HC,
            WsL + l * EMB * HC, bsL + l * HC,
            Q, kvh, Outb);
        edge_attn_kernel<<<NN / 4, 256, 0, stream>>>(row_ptr, ssrc, sea,
            WeL + l * EDIM * HC, Q, kvu, Outb);
        transform_kernel<<<(NN * EMB + 255) / 256, 256, 0, stream>>>(Outb,
            WtL + l * HC * EMB, btL + l * EMB, hbuf);
    }

    // ---- dense head ----
    head_kernel<<<NN / 4, 256, 0, stream>>>(hbuf, W1, b1, W2, b2, W3, b3, out);
}

// Round 7
// 807.571 us; speedup vs baseline: 1.4573x; 1.1327x over previous
//
#include <hip/hip_runtime.h>

#define NN 50000
#define EE 800000
#define FIN 16
#define EDIM 4
#define EMB 32
#define NH 4
#define HC 128          // EMB*NH
#define NL 2
#define DENSE 128
#define QNPB 50         // nodes per qkvs block (50000 = 1000 * 50)
#define SBLK 49         // scan blocks: ceil(50000/1024)

// unpack two packed fp16 -> float2
__device__ __forceinline__ float2 h2f2(unsigned int u) {
    union { unsigned int u; _Float16 h[2]; } c; c.u = u;
    return make_float2((float)c.h[0], (float)c.h[1]);
}

// ---------------- CSR build ----------------
__global__ void hist_kernel(const int* __restrict__ dst, int* __restrict__ counts) {
    int e = blockIdx.x * blockDim.x + threadIdx.x;
    if (e < EE) atomicAdd(&counts[dst[e]], 1);
}

// hierarchical scan, stage 1: block-local exclusive scan (1 elem/thread), emit block sums
__global__ __launch_bounds__(1024) void scan1_kernel(const int* __restrict__ cursor,
                                                     int* __restrict__ row_ptr,
                                                     int* __restrict__ bsum) {
    __shared__ int wsum[16];
    __shared__ int wpre[17];
    int tid = threadIdx.x, lane = tid & 63, wid = tid >> 6;
    int i = blockIdx.x * 1024 + tid;
    int v = (i < NN) ? cursor[i] : 0;
    int incl = v;
    #pragma unroll
    for (int off = 1; off < 64; off <<= 1) {
        int t = __shfl_up(incl, off, 64);
        if (lane >= off) incl += t;
    }
    if (lane == 63) wsum[wid] = incl;
    __syncthreads();
    if (tid == 0) {
        int acc = 0;
        #pragma unroll
        for (int w = 0; w < 16; ++w) { wpre[w] = acc; acc += wsum[w]; }
        wpre[16] = acc;
    }
    __syncthreads();
    if (i < NN) row_ptr[i] = wpre[wid] + incl - v;    // block-local exclusive
    if (tid == 0) bsum[blockIdx.x] = wpre[16];
}

// stage 2: one wave scans the SBLK block sums (exclusive), writes grand total
__global__ void scan2_kernel(int* __restrict__ bsum, int* __restrict__ row_ptr) {
    int t = threadIdx.x;                               // 64 threads
    int v = (t < SBLK) ? bsum[t] : 0;
    int incl = v;
    #pragma unroll
    for (int off = 1; off < 64; off <<= 1) {
        int u = __shfl_up(incl, off, 64);
        if (t >= off) incl += u;
    }
    if (t < SBLK) bsum[t] = incl - v;                  // exclusive
    if (t == 63) row_ptr[NN] = incl;                   // total == EE
}

// stage 3: add block offsets; mirror into cursor for the scatter pass
__global__ __launch_bounds__(1024) void scan3_kernel(int* __restrict__ row_ptr,
                                                     int* __restrict__ cursor,
                                                     const int* __restrict__ bsum) {
    int i = blockIdx.x * 1024 + threadIdx.x;
    if (i >= NN) return;
    int r = row_ptr[i] + bsum[blockIdx.x];
    row_ptr[i] = r;
    cursor[i] = r;
}

__global__ void scatter_kernel(const int* __restrict__ src, const int* __restrict__ dst,
                               const float* __restrict__ ea, int* __restrict__ cursor,
                               int* __restrict__ ssrc, unsigned long long* __restrict__ sea) {
    int e = blockIdx.x * blockDim.x + threadIdx.x;
    if (e >= EE) return;
    int d = dst[e];
    int pos = atomicAdd(&cursor[d], 1);
    ssrc[pos] = src[e];
    float4 q = *reinterpret_cast<const float4*>(ea + (size_t)e * 4);
    union { unsigned long long u; _Float16 h[4]; } pk;
    pk.h[0] = (_Float16)q.x; pk.h[1] = (_Float16)q.y;
    pk.h[2] = (_Float16)q.z; pk.h[3] = (_Float16)q.w;
    sea[pos] = pk.u;
}

// ---------------- node projections: Q f32, K/V packed fp16, skip f32 into Out ----------
// Weights live in REGISTERS (F per thread), looped over QNPB nodes per block.
template<int F>
__global__ __launch_bounds__(512) void qkvs_kernel(const float* __restrict__ hin,
        const float* __restrict__ Wq, const float* __restrict__ bq,
        const float* __restrict__ Wk, const float* __restrict__ bk,
        const float* __restrict__ Wv, const float* __restrict__ bv,
        const float* __restrict__ Ws, const float* __restrict__ bs,
        float* __restrict__ Q, _Float16* __restrict__ kvh,
        float* __restrict__ Out) {
    __shared__ float hs[QNPB][F];
    int tid = threadIdx.x;
    int m = tid >> 7, c = tid & 127;
    const float* W; const float* b;
    switch (m) {
        case 0:  W = Wq; b = bq; break;
        case 1:  W = Wk; b = bk; break;
        case 2:  W = Wv; b = bv; break;
        default: W = Ws; b = bs; break;
    }
    float w[F];
    #pragma unroll
    for (int f = 0; f < F; ++f) w[f] = W[f * HC + c];   // column c, coalesced per group
    float bias = b[c];

    int node0 = blockIdx.x * QNPB;
    for (int i = tid; i < QNPB * F; i += 512)
        hs[i / F][i % F] = hin[(size_t)node0 * F + i];
    __syncthreads();

    for (int k = 0; k < QNPB; ++k) {
        float s = bias;
        #pragma unroll
        for (int f = 0; f < F; ++f) s += hs[k][f] * w[f];   // LDS broadcast
        size_t n = node0 + k;
        if      (m == 0) Q[n * HC + c] = s;
        else if (m == 1) kvh[n * 256 + 2 * c] = (_Float16)s;       // K -> low half
        else if (m == 2) kvh[n * 256 + 2 * c + 1] = (_Float16)s;   // V -> high half
        else             Out[n * HC + c] = s;
    }
}

// ---------------- edge attention (one wave per dst node), fp16 KV gather ----------------
__global__ __launch_bounds__(256) void edge_attn_kernel(const int* __restrict__ row_ptr,
        const int* __restrict__ ssrc, const unsigned long long* __restrict__ sea,
        const float* __restrict__ We,
        const float* __restrict__ Q, const unsigned int* __restrict__ kv,
        float* __restrict__ Out) {
    int n = blockIdx.x * 4 + (threadIdx.x >> 6);   // grid*4 == NN exactly
    int lane = threadIdx.x & 63;
    int c0 = lane, c1 = lane + 64;
    float we0[4], we1[4];
    #pragma unroll
    for (int d = 0; d < 4; ++d) { we0[d] = We[d * HC + c0]; we1[d] = We[d * HC + c1]; }
    float q0 = Q[(size_t)n * HC + c0], q1 = Q[(size_t)n * HC + c1];
    int start = row_ptr[n], end = row_ptr[n + 1];
    float m0 = -INFINITY, z0 = 0.f, a0 = 0.f;
    float m1 = -INFINITY, z1 = 0.f, a1 = 0.f;
    const float SC = 0.17677669529663687f;  // 1/sqrt(32)
    int i = start;
    for (; i + 1 < end; i += 2) {
        int sA = ssrc[i], sB = ssrc[i + 1];
        sA = sA < 0 ? 0 : (sA >= NN ? NN - 1 : sA);
        sB = sB < 0 ? 0 : (sB >= NN ? NN - 1 : sB);
        unsigned long long epA = sea[i], epB = sea[i + 1];
        unsigned int kvA0 = kv[(size_t)sA * 128 + c0], kvA1 = kv[(size_t)sA * 128 + c1];
        unsigned int kvB0 = kv[(size_t)sB * 128 + c0], kvB1 = kv[(size_t)sB * 128 + c1];
        float2 eaA01 = h2f2((unsigned int)epA), eaA23 = h2f2((unsigned int)(epA >> 32));
        float2 eaB01 = h2f2((unsigned int)epB), eaB23 = h2f2((unsigned int)(epB >> 32));
        float eA0 = eaA01.x * we0[0] + eaA01.y * we0[1] + eaA23.x * we0[2] + eaA23.y * we0[3];
        float eA1 = eaA01.x * we1[0] + eaA01.y * we1[1] + eaA23.x * we1[2] + eaA23.y * we1[3];
        float eB0 = eaB01.x * we0[0] + eaB01.y * we0[1] + eaB23.x * we0[2] + eaB23.y * we0[3];
        float eB1 = eaB01.x * we1[0] + eaB01.y * we1[1] + eaB23.x * we1[2] + eaB23.y * we1[3];
        float2 kA0 = h2f2(kvA0), kA1 = h2f2(kvA1);
        float2 kB0 = h2f2(kvB0), kB1 = h2f2(kvB1);
        float pA0 = q0 * (kA0.x + eA0), pA1 = q1 * (kA1.x + eA1);
        float pB0 = q0 * (kB0.x + eB0), pB1 = q1 * (kB1.x + eB1);
        #pragma unroll
        for (int off = 1; off < 32; off <<= 1) {
            pA0 += __shfl_xor(pA0, off, 64);
            pA1 += __shfl_xor(pA1, off, 64);
            pB0 += __shfl_xor(pB0, off, 64);
            pB1 += __shfl_xor(pB1, off, 64);
        }
        float lA0 = pA0 * SC, lA1 = pA1 * SC, lB0 = pB0 * SC, lB1 = pB1 * SC;
        float vA0 = kA0.y + eA0, vA1 = kA1.y + eA1;
        float vB0 = kB0.y + eB0, vB1 = kB1.y + eB1;
        float nm0 = fmaxf(m0, fmaxf(lA0, lB0));
        float nm1 = fmaxf(m1, fmaxf(lA1, lB1));
        float sc0 = __expf(m0 - nm0), xA0 = __expf(lA0 - nm0), xB0 = __expf(lB0 - nm0);
        float sc1 = __expf(m1 - nm1), xA1 = __expf(lA1 - nm1), xB1 = __expf(lB1 - nm1);
        a0 = a0 * sc0 + xA0 * vA0 + xB0 * vB0;  z0 = z0 * sc0 + xA0 + xB0;  m0 = nm0;
        a1 = a1 * sc1 + xA1 * vA1 + xB1 * vB1;  z1 = z1 * sc1 + xA1 + xB1;  m1 = nm1;
    }
    if (i < end) {
        int s = ssrc[i];
        s = s < 0 ? 0 : (s >= NN ? NN - 1 : s);
        unsigned long long ep = sea[i];
        unsigned int kv0 = kv[(size_t)s * 128 + c0], kv1 = kv[(size_t)s * 128 + c1];
        float2 ea01 = h2f2((unsigned int)ep), ea23 = h2f2((unsigned int)(ep >> 32));
        float e0 = ea01.x * we0[0] + ea01.y * we0[1] + ea23.x * we0[2] + ea23.y * we0[3];
        float e1 = ea01.x * we1[0] + ea01.y * we1[1] + ea23.x * we1[2] + ea23.y * we1[3];
        float2 k0 = h2f2(kv0), k1 = h2f2(kv1);
        float p0 = q0 * (k0.x + e0), p1 = q1 * (k1.x + e1);
        #pragma unroll
        for (int off = 1; off < 32; off <<= 1) {
            p0 += __shfl_xor(p0, off, 64);
            p1 += __shfl_xor(p1, off, 64);
        }
        float l0 = p0 * SC, l1 = p1 * SC;
        float nm0 = fmaxf(m0, l0), nm1 = fmaxf(m1, l1);
        float sc0 = __expf(m0 - nm0), x0 = __expf(l0 - nm0);
        float sc1 = __expf(m1 - nm1), x1 = __expf(l1 - nm1);
        a0 = a0 * sc0 + x0 * (k0.y + e0);  z0 = z0 * sc0 + x0;  m0 = nm0;
        a1 = a1 * sc1 + x1 * (k1.y + e1);  z1 = z1 * sc1 + x1;  m1 = nm1;
    }
    Out[(size_t)n * HC + c0] += a0 / (z0 + 1e-16f);
    Out[(size_t)n * HC + c1] += a1 / (z1 + 1e-16f);
}

// ---------------- h = relu(Out @ Wt + bt), float4 row loads ----------------
__global__ void transform_kernel(const float* __restrict__ Out, const float* __restrict__ Wt,
                                 const float* __restrict__ bt, float* __restrict__ h) {
    int idx = blockIdx.x * blockDim.x + threadIdx.x;
    if (idx >= NN * EMB) return;
    int n = idx >> 5, c = idx & 31;
    const float4* r4 = (const float4*)(Out + (size_t)n * HC);
    float s = bt[c];
    #pragma unroll 8
    for (int j = 0; j < 32; ++j) {
        float4 rv = r4[j];
        const float* wp = Wt + (4 * j) * EMB + c;
        s += rv.x * wp[0] + rv.y * wp[EMB] + rv.z * wp[2 * EMB] + rv.w * wp[3 * EMB];
    }
    h[idx] = fmaxf(s, 0.f);
}

// ---------------- fused dense head (wave per node), f32 output ----------------
__global__ __launch_bounds__(256) void head_kernel(const float* __restrict__ h,
        const float* __restrict__ W1, const float* __restrict__ b1,
        const float* __restrict__ W2, const float* __restrict__ b2,
        const float* __restrict__ W3, const float* __restrict__ b3,
        float* __restrict__ out) {
    __shared__ float sh[4][EMB];
    __shared__ float sd1[4][DENSE];
    int wid = threadIdx.x >> 6, lane = threadIdx.x & 63;
    int n = blockIdx.x * 4 + wid;           // NN % 4 == 0
    if (lane < EMB) sh[wid][lane] = h[(size_t)n * EMB + lane];
    __syncthreads();
    float s0 = b1[lane], s1 = b1[lane + 64];
    #pragma unroll
    for (int f = 0; f < EMB; ++f) {
        float hv = sh[wid][f];
        s0 += hv * W1[f * DENSE + lane];
        s1 += hv * W1[f * DENSE + lane + 64];
    }
    sd1[wid][lane] = fmaxf(s0, 0.f);
    sd1[wid][lane + 64] = fmaxf(s1, 0.f);
    __syncthreads();
    float s2 = b2[lane];
    #pragma unroll 8
    for (int j = 0; j < DENSE; ++j) s2 += sd1[wid][j] * W2[j * 64 + lane];
    s2 = fmaxf(s2, 0.f);
    float t = s2 * W3[lane];
    #pragma unroll
    for (int off = 1; off < 64; off <<= 1) t += __shfl_xor(t, off, 64);
    if (lane == 0) {
        float x = t + b3[0];
        out[n] = 1.f / (1.f + __expf(-x));
    }
}

extern "C" void kernel_launch(void* const* d_in, const int* in_sizes, int n_in,
                              void* d_out, int out_size, void* d_ws, size_t ws_size,
                              hipStream_t stream) {
    const float* x   = (const float*)d_in[0];
    const int*   ei  = (const int*)d_in[1];    // [2,E]: src=ei, dst=ei+E
    const float* ea  = (const float*)d_in[2];
    const float* Wq0 = (const float*)d_in[3];  const float* bq0 = (const float*)d_in[4];
    const float* Wk0 = (const float*)d_in[5];  const float* bk0 = (const float*)d_in[6];
    const float* Wv0 = (const float*)d_in[7];  const float* bv0 = (const float*)d_in[8];
    const float* We0 = (const float*)d_in[9];
    const float* Ws0 = (const float*)d_in[10]; const float* bs0 = (const float*)d_in[11];
    const float* Wt0 = (const float*)d_in[12]; const float* bt0 = (const float*)d_in[13];
    const float* WqL = (const float*)d_in[14]; const float* bqL = (const float*)d_in[15];
    const float* WkL = (const float*)d_in[16]; const float* bkL = (const float*)d_in[17];
    const float* WvL = (const float*)d_in[18]; const float* bvL = (const float*)d_in[19];
    const float* WeL = (const float*)d_in[20];
    const float* WsL = (const float*)d_in[21]; const float* bsL = (const float*)d_in[22];
    const float* WtL = (const float*)d_in[23]; const float* btL = (const float*)d_in[24];
    const float* W1  = (const float*)d_in[25]; const float* b1  = (const float*)d_in[26];
    const float* W2  = (const float*)d_in[27]; const float* b2  = (const float*)d_in[28];
    const float* W3  = (const float*)d_in[29]; const float* b3  = (const float*)d_in[30];
    float* out = (float*)d_out;

    char* ws = (char*)d_ws;
    size_t off = 0;
    auto alloc = [&](size_t bytes) -> void* {
        void* p = ws + off; off = (off + bytes + 255) & ~(size_t)255; return p;
    };
    int*     cursor  = (int*)    alloc((size_t)NN * 4);
    int*     row_ptr = (int*)    alloc((size_t)(NN + 1) * 4);
    int*     bsum    = (int*)    alloc((size_t)SBLK * 4);
    int*     ssrc    = (int*)    alloc((size_t)EE * 4);
    unsigned long long* sea = (unsigned long long*)alloc((size_t)EE * 8);
    float*   hbuf    = (float*)  alloc((size_t)NN * EMB * 4);
    float*   Q       = (float*)  alloc((size_t)NN * HC * 4);
    _Float16* kvh    = (_Float16*)alloc((size_t)NN * HC * 2 * 2);  // packed (k,v) per channel
    float*   Outb    = (float*)  alloc((size_t)NN * HC * 4);
    // total ~93 MB

    // ---- CSR by dst (edge_index shared by all 3 conv layers) ----
    hipMemsetAsync(cursor, 0, (size_t)NN * 4, stream);
    hist_kernel<<<(EE + 255) / 256, 256, 0, stream>>>(ei + EE, cursor);
    scan1_kernel<<<SBLK, 1024, 0, stream>>>(cursor, row_ptr, bsum);
    scan2_kernel<<<1, 64, 0, stream>>>(bsum, row_ptr);
    scan3_kernel<<<SBLK, 1024, 0, stream>>>(row_ptr, cursor, bsum);
    scatter_kernel<<<(EE + 255) / 256, 256, 0, stream>>>(ei, ei + EE, ea, cursor, ssrc, sea);

    const unsigned int* kvu = (const unsigned int*)kvh;

    // ---- layer 0 (F_IN=16) ----
    qkvs_kernel<FIN><<<NN / QNPB, 512, 0, stream>>>(x, Wq0, bq0, Wk0, bk0, Wv0, bv0,
                                                    Ws0, bs0, Q, kvh, Outb);
    edge_attn_kernel<<<NN / 4, 256, 0, stream>>>(row_ptr, ssrc, sea, We0, Q, kvu, Outb);
    transform_kernel<<<(NN * EMB + 255) / 256, 256, 0, stream>>>(Outb, Wt0, bt0, hbuf);

    // ---- inner layers (F=EMB=32) ----
    for (int l = 0; l < NL; ++l) {
        qkvs_kernel<EMB><<<NN / QNPB, 512, 0, stream>>>(hbuf,
            WqL + l * EMB * HC, bqL + l * HC,
            WkL + l * EMB * HC, bkL + l * HC,
            WvL + l * EMB * HC, bvL + l * HC,
            WsL + l * EMB * HC, bsL + l * HC,
            Q, kvh, Outb);
        edge_attn_kernel<<<NN / 4, 256, 0, stream>>>(row_ptr, ssrc, sea,
            WeL + l * EDIM * HC, Q, kvu, Outb);
        transform_kernel<<<(NN * EMB + 255) / 256, 256, 0, stream>>>(Outb,
            WtL + l * HC * EMB, btL + l * EMB, hbuf);
    }

    // ---- dense head ----
    head_kernel<<<NN / 4, 256, 0, stream>>>(hbuf, W1, b1, W2, b2, W3, b3, out);
}

// Round 8
// 699.204 us; speedup vs baseline: 1.6831x; 1.1550x over previous
//
#include <hip/hip_runtime.h>

#define NN 50000
#define EE 800000
#define FIN 16
#define EDIM 4
#define EMB 32
#define NH 4
#define HC 128          // EMB*NH
#define NL 2
#define DENSE 128
#define QNPB 50         // nodes per qkvs/ftq block (50000 = 1000 * 50)
#define SBLK 49         // scan blocks: ceil(50000/1024)

// unpack two packed fp16 -> float2
__device__ __forceinline__ float2 h2f2(unsigned int u) {
    union { unsigned int u; _Float16 h[2]; } c; c.u = u;
    return make_float2((float)c.h[0], (float)c.h[1]);
}

// ---------------- CSR build ----------------
__global__ void hist_kernel(const int* __restrict__ dst, int* __restrict__ counts) {
    int e = blockIdx.x * blockDim.x + threadIdx.x;
    if (e < EE) atomicAdd(&counts[dst[e]], 1);
}

__global__ __launch_bounds__(1024) void scan1_kernel(const int* __restrict__ cursor,
                                                     int* __restrict__ row_ptr,
                                                     int* __restrict__ bsum) {
    __shared__ int wsum[16];
    __shared__ int wpre[17];
    int tid = threadIdx.x, lane = tid & 63, wid = tid >> 6;
    int i = blockIdx.x * 1024 + tid;
    int v = (i < NN) ? cursor[i] : 0;
    int incl = v;
    #pragma unroll
    for (int off = 1; off < 64; off <<= 1) {
        int t = __shfl_up(incl, off, 64);
        if (lane >= off) incl += t;
    }
    if (lane == 63) wsum[wid] = incl;
    __syncthreads();
    if (tid == 0) {
        int acc = 0;
        #pragma unroll
        for (int w = 0; w < 16; ++w) { wpre[w] = acc; acc += wsum[w]; }
        wpre[16] = acc;
    }
    __syncthreads();
    if (i < NN) row_ptr[i] = wpre[wid] + incl - v;
    if (tid == 0) bsum[blockIdx.x] = wpre[16];
}

__global__ void scan2_kernel(int* __restrict__ bsum, int* __restrict__ row_ptr) {
    int t = threadIdx.x;                               // 64 threads
    int v = (t < SBLK) ? bsum[t] : 0;
    int incl = v;
    #pragma unroll
    for (int off = 1; off < 64; off <<= 1) {
        int u = __shfl_up(incl, off, 64);
        if (t >= off) incl += u;
    }
    if (t < SBLK) bsum[t] = incl - v;
    if (t == 63) row_ptr[NN] = incl;
}

__global__ __launch_bounds__(1024) void scan3_kernel(int* __restrict__ row_ptr,
                                                     int* __restrict__ cursor,
                                                     const int* __restrict__ bsum) {
    int i = blockIdx.x * 1024 + threadIdx.x;
    if (i >= NN) return;
    int r = row_ptr[i] + bsum[blockIdx.x];
    row_ptr[i] = r;
    cursor[i] = r;
}

__global__ void scatter_kernel(const int* __restrict__ src, const int* __restrict__ dst,
                               const float* __restrict__ ea, int* __restrict__ cursor,
                               int* __restrict__ ssrc, float4* __restrict__ sea) {
    int e = blockIdx.x * blockDim.x + threadIdx.x;
    if (e >= EE) return;
    int d = dst[e];
    int pos = atomicAdd(&cursor[d], 1);
    ssrc[pos] = src[e];
    sea[pos] = *reinterpret_cast<const float4*>(ea + (size_t)e * 4);
}

// ---------------- layer-0 projections: Q f32, K/V packed fp16, skip into Out --------
__global__ __launch_bounds__(512) void qkvs0_kernel(const float* __restrict__ x,
        const float* __restrict__ Wq, const float* __restrict__ bq,
        const float* __restrict__ Wk, const float* __restrict__ bk,
        const float* __restrict__ Wv, const float* __restrict__ bv,
        const float* __restrict__ Ws, const float* __restrict__ bs,
        float* __restrict__ Q, _Float16* __restrict__ kvh,
        float* __restrict__ Out) {
    __shared__ float hs[QNPB][FIN];
    int tid = threadIdx.x;
    int m = tid >> 7, c = tid & 127;
    const float* W; const float* b;
    switch (m) {
        case 0:  W = Wq; b = bq; break;
        case 1:  W = Wk; b = bk; break;
        case 2:  W = Wv; b = bv; break;
        default: W = Ws; b = bs; break;
    }
    float w[FIN];
    #pragma unroll
    for (int f = 0; f < FIN; ++f) w[f] = W[f * HC + c];
    float bias = b[c];
    int node0 = blockIdx.x * QNPB;
    for (int i = tid; i < QNPB * FIN; i += 512)
        hs[i / FIN][i % FIN] = x[(size_t)node0 * FIN + i];
    __syncthreads();
    for (int k = 0; k < QNPB; ++k) {
        float s = bias;
        #pragma unroll
        for (int f = 0; f < FIN; ++f) s += hs[k][f] * w[f];
        size_t n = node0 + k;
        if      (m == 0) Q[n * HC + c] = s;
        else if (m == 1) kvh[n * 256 + 2 * c] = (_Float16)s;
        else if (m == 2) kvh[n * 256 + 2 * c + 1] = (_Float16)s;
        else             Out[n * HC + c] = s;
    }
}

// ---------- fused transform + projections: h = relu(Out@Wt+bt) (LDS), then QKVS ------
__global__ __launch_bounds__(512) void ftq_kernel(const float* __restrict__ Wt,
        const float* __restrict__ bt,
        const float* __restrict__ Wq, const float* __restrict__ bq,
        const float* __restrict__ Wk, const float* __restrict__ bk,
        const float* __restrict__ Wv, const float* __restrict__ bv,
        const float* __restrict__ Ws, const float* __restrict__ bs,
        float* __restrict__ Q, _Float16* __restrict__ kvh,
        float* __restrict__ Out) {
    __shared__ float os[QNPB * HC];     // 25.6 KB
    __shared__ float hs[QNPB][EMB];     // 6.4 KB
    int tid = threadIdx.x;
    int node0 = blockIdx.x * QNPB;
    for (int i = tid; i < QNPB * HC; i += 512)
        os[i] = Out[(size_t)node0 * HC + i];
    __syncthreads();
    for (int idx = tid; idx < QNPB * EMB; idx += 512) {
        int nl = idx >> 5, c = idx & 31;
        float s = bt[c];
        const float* r = os + nl * HC;
        #pragma unroll 8
        for (int j = 0; j < HC; ++j) s += r[j] * Wt[j * EMB + c];
        hs[nl][c] = fmaxf(s, 0.f);
    }
    __syncthreads();
    int m = tid >> 7, c = tid & 127;
    const float* W; const float* b;
    switch (m) {
        case 0:  W = Wq; b = bq; break;
        case 1:  W = Wk; b = bk; break;
        case 2:  W = Wv; b = bv; break;
        default: W = Ws; b = bs; break;
    }
    float w[EMB];
    #pragma unroll
    for (int f = 0; f < EMB; ++f) w[f] = W[f * HC + c];
    float bias = b[c];
    for (int k = 0; k < QNPB; ++k) {
        float s = bias;
        #pragma unroll
        for (int f = 0; f < EMB; ++f) s += hs[k][f] * w[f];
        size_t n = node0 + k;
        if      (m == 0) Q[n * HC + c] = s;
        else if (m == 1) kvh[n * 256 + 2 * c] = (_Float16)s;
        else if (m == 2) kvh[n * 256 + 2 * c + 1] = (_Float16)s;
        else             Out[n * HC + c] = s;
    }
}

// ------- edge attention: lane = channel pair, head = lane>>4, no-max softmax ---------
__global__ __launch_bounds__(256) void edge_attn_kernel(const int* __restrict__ row_ptr,
        const int* __restrict__ ssrc, const float4* __restrict__ sea,
        const float* __restrict__ We,
        const float* __restrict__ Q, const uint2* __restrict__ kvp,
        float2* __restrict__ Out) {
    int n = blockIdx.x * 4 + (threadIdx.x >> 6);   // grid*4 == NN exactly
    int lane = threadIdx.x & 63;
    int ch0 = 2 * lane, ch1 = 2 * lane + 1;
    float we0[4], we1[4];
    #pragma unroll
    for (int d = 0; d < 4; ++d) { we0[d] = We[d * HC + ch0]; we1[d] = We[d * HC + ch1]; }
    float2 q = ((const float2*)Q)[(size_t)n * 64 + lane];
    int start = row_ptr[n], end = row_ptr[n + 1];
    float z = 0.f, acc0 = 0.f, acc1 = 0.f;
    const float SC = 0.17677669529663687f;  // 1/sqrt(32)
    int i = start;
    for (; i + 1 < end; i += 2) {
        int sA = ssrc[i], sB = ssrc[i + 1];
        sA = sA < 0 ? 0 : (sA >= NN ? NN - 1 : sA);
        sB = sB < 0 ? 0 : (sB >= NN ? NN - 1 : sB);
        float4 eA = sea[i], eB = sea[i + 1];                     // wave-uniform
        uint2 kvA = kvp[(size_t)sA * 64 + lane];                 // k0,v0,k1,v1 fp16
        uint2 kvB = kvp[(size_t)sB * 64 + lane];
        float eA0 = eA.x * we0[0] + eA.y * we0[1] + eA.z * we0[2] + eA.w * we0[3];
        float eA1 = eA.x * we1[0] + eA.y * we1[1] + eA.z * we1[2] + eA.w * we1[3];
        float eB0 = eB.x * we0[0] + eB.y * we0[1] + eB.z * we0[2] + eB.w * we0[3];
        float eB1 = eB.x * we1[0] + eB.y * we1[1] + eB.z * we1[2] + eB.w * we1[3];
        float2 kvA0 = h2f2(kvA.x), kvA1 = h2f2(kvA.y);           // (k,v) ch0 / ch1
        float2 kvB0 = h2f2(kvB.x), kvB1 = h2f2(kvB.y);
        float pA = q.x * (kvA0.x + eA0) + q.y * (kvA1.x + eA1);
        float pB = q.x * (kvB0.x + eB0) + q.y * (kvB1.x + eB1);
        #pragma unroll
        for (int off = 1; off < 16; off <<= 1) {                 // 16-lane head groups
            pA += __shfl_xor(pA, off, 64);
            pB += __shfl_xor(pB, off, 64);
        }
        float xA = __expf(pA * SC), xB = __expf(pB * SC);
        z += xA + xB;
        acc0 += xA * (kvA0.y + eA0) + xB * (kvB0.y + eB0);
        acc1 += xA * (kvA1.y + eA1) + xB * (kvB1.y + eB1);
    }
    if (i < end) {
        int s = ssrc[i];
        s = s < 0 ? 0 : (s >= NN ? NN - 1 : s);
        float4 e = sea[i];
        uint2 kv = kvp[(size_t)s * 64 + lane];
        float e0 = e.x * we0[0] + e.y * we0[1] + e.z * we0[2] + e.w * we0[3];
        float e1 = e.x * we1[0] + e.y * we1[1] + e.z * we1[2] + e.w * we1[3];
        float2 kv0 = h2f2(kv.x), kv1 = h2f2(kv.y);
        float p = q.x * (kv0.x + e0) + q.y * (kv1.x + e1);
        #pragma unroll
        for (int off = 1; off < 16; off <<= 1) p += __shfl_xor(p, off, 64);
        float x = __expf(p * SC);
        z += x;
        acc0 += x * (kv0.y + e0);
        acc1 += x * (kv1.y + e1);
    }
    float inv = 1.f / (z + 1e-16f);
    size_t oi = (size_t)n * 64 + lane;
    float2 o = Out[oi];
    o.x += acc0 * inv;
    o.y += acc1 * inv;
    Out[oi] = o;
}

// -------- fused final transform + dense head (wave per node), f32 output -------------
__global__ __launch_bounds__(256) void th_kernel(const float* __restrict__ Outb,
        const float* __restrict__ Wt, const float* __restrict__ bt,
        const float* __restrict__ W1, const float* __restrict__ b1,
        const float* __restrict__ W2, const float* __restrict__ b2,
        const float* __restrict__ W3, const float* __restrict__ b3,
        float* __restrict__ out) {
    __shared__ float sh[4][EMB];
    __shared__ float sd1[4][DENSE];
    int wid = threadIdx.x >> 6, lane = threadIdx.x & 63;
    int n = blockIdx.x * 4 + wid;           // NN % 4 == 0
    int c = lane & 31, half = lane >> 5;
    // h[c] = relu(bt[c] + Outb[n,:] @ Wt[:,c]) split across lane halves
    const float* orow = Outb + (size_t)n * HC;
    float s = 0.f;
    int j0 = half * 64;
    #pragma unroll 8
    for (int j = j0; j < j0 + 64; ++j) s += orow[j] * Wt[j * EMB + c];
    s += __shfl_xor(s, 32, 64);
    if (half == 0) sh[wid][c] = fmaxf(s + bt[c], 0.f);
    __syncthreads();
    float s0 = b1[lane], s1 = b1[lane + 64];
    #pragma unroll
    for (int f = 0; f < EMB; ++f) {
        float hv = sh[wid][f];
        s0 += hv * W1[f * DENSE + lane];
        s1 += hv * W1[f * DENSE + lane + 64];
    }
    sd1[wid][lane] = fmaxf(s0, 0.f);
    sd1[wid][lane + 64] = fmaxf(s1, 0.f);
    __syncthreads();
    float s2 = b2[lane];
    #pragma unroll 8
    for (int j = 0; j < DENSE; ++j) s2 += sd1[wid][j] * W2[j * 64 + lane];
    s2 = fmaxf(s2, 0.f);
    float t = s2 * W3[lane];
    #pragma unroll
    for (int off = 1; off < 64; off <<= 1) t += __shfl_xor(t, off, 64);
    if (lane == 0) {
        float xx = t + b3[0];
        out[n] = 1.f / (1.f + __expf(-xx));
    }
}

extern "C" void kernel_launch(void* const* d_in, const int* in_sizes, int n_in,
                              void* d_out, int out_size, void* d_ws, size_t ws_size,
                              hipStream_t stream) {
    const float* x   = (const float*)d_in[0];
    const int*   ei  = (const int*)d_in[1];    // [2,E]: src=ei, dst=ei+E
    const float* ea  = (const float*)d_in[2];
    const float* Wq0 = (const float*)d_in[3];  const float* bq0 = (const float*)d_in[4];
    const float* Wk0 = (const float*)d_in[5];  const float* bk0 = (const float*)d_in[6];
    const float* Wv0 = (const float*)d_in[7];  const float* bv0 = (const float*)d_in[8];
    const float* We0 = (const float*)d_in[9];
    const float* Ws0 = (const float*)d_in[10]; const float* bs0 = (const float*)d_in[11];
    const float* Wt0 = (const float*)d_in[12]; const float* bt0 = (const float*)d_in[13];
    const float* WqL = (const float*)d_in[14]; const float* bqL = (const float*)d_in[15];
    const float* WkL = (const float*)d_in[16]; const float* bkL = (const float*)d_in[17];
    const float* WvL = (const float*)d_in[18]; const float* bvL = (const float*)d_in[19];
    const float* WeL = (const float*)d_in[20];
    const float* WsL = (const float*)d_in[21]; const float* bsL = (const float*)d_in[22];
    const float* WtL = (const float*)d_in[23]; const float* btL = (const float*)d_in[24];
    const float* W1  = (const float*)d_in[25]; const float* b1  = (const float*)d_in[26];
    const float* W2  = (const float*)d_in[27]; const float* b2  = (const float*)d_in[28];
    const float* W3  = (const float*)d_in[29]; const float* b3  = (const float*)d_in[30];
    float* out = (float*)d_out;

    char* ws = (char*)d_ws;
    size_t off = 0;
    auto alloc = [&](size_t bytes) -> void* {
        void* p = ws + off; off = (off + bytes + 255) & ~(size_t)255; return p;
    };
    int*     cursor  = (int*)    alloc((size_t)NN * 4);
    int*     row_ptr = (int*)    alloc((size_t)(NN + 1) * 4);
    int*     bsum    = (int*)    alloc((size_t)SBLK * 4);
    int*     ssrc    = (int*)    alloc((size_t)EE * 4);
    float4*  sea     = (float4*) alloc((size_t)EE * 16);
    float*   Q       = (float*)  alloc((size_t)NN * HC * 4);
    _Float16* kvh    = (_Float16*)alloc((size_t)NN * HC * 2 * 2);  // (k,v) interleaved
    float*   Outb    = (float*)  alloc((size_t)NN * HC * 4);
    // total ~93 MB

    // ---- CSR by dst (edge_index shared by all 3 conv layers) ----
    hipMemsetAsync(cursor, 0, (size_t)NN * 4, stream);
    hist_kernel<<<(EE + 255) / 256, 256, 0, stream>>>(ei + EE, cursor);
    scan1_kernel<<<SBLK, 1024, 0, stream>>>(cursor, row_ptr, bsum);
    scan2_kernel<<<1, 64, 0, stream>>>(bsum, row_ptr);
    scan3_kernel<<<SBLK, 1024, 0, stream>>>(row_ptr, cursor, bsum);
    scatter_kernel<<<(EE + 255) / 256, 256, 0, stream>>>(ei, ei + EE, ea, cursor, ssrc, sea);

    const uint2* kvp = (const uint2*)kvh;
    float2* Out2 = (float2*)Outb;

    // ---- layer 0 ----
    qkvs0_kernel<<<NN / QNPB, 512, 0, stream>>>(x, Wq0, bq0, Wk0, bk0, Wv0, bv0,
                                                Ws0, bs0, Q, kvh, Outb);
    edge_attn_kernel<<<NN / 4, 256, 0, stream>>>(row_ptr, ssrc, sea, We0, Q, kvp, Out2);

    // ---- layer 1: fused transform(Wt0) + projections(WqL[0]) ----
    ftq_kernel<<<NN / QNPB, 512, 0, stream>>>(Wt0, bt0,
        WqL, bqL, WkL, bkL, WvL, bvL, WsL, bsL, Q, kvh, Outb);
    edge_attn_kernel<<<NN / 4, 256, 0, stream>>>(row_ptr, ssrc, sea, WeL, Q, kvp, Out2);

    // ---- layer 2: fused transform(Wt[0]) + projections(WqL[1]) ----
    ftq_kernel<<<NN / QNPB, 512, 0, stream>>>(WtL, btL,
        WqL + EMB * HC, bqL + HC, WkL + EMB * HC, bkL + HC,
        WvL + EMB * HC, bvL + HC, WsL + EMB * HC, bsL + HC, Q, kvh, Outb);
    edge_attn_kernel<<<NN / 4, 256, 0, stream>>>(row_ptr, ssrc, sea,
        WeL + EDIM * HC, Q, kvp, Out2);

    // ---- fused final transform(Wt[1]) + dense head ----
    th_kernel<<<NN / 4, 256, 0, stream>>>(Outb, WtL + (size_t)HC * EMB, btL + EMB,
                                          W1, b1, W2, b2, W3, b3, out);
}

// Round 9
// 652.270 us; speedup vs baseline: 1.8042x; 1.0720x over previous
//
#include <hip/hip_runtime.h>

#define NN 50000
#define EE 800000
#define FIN 16
#define EDIM 4
#define EMB 32
#define NH 4
#define HC 128          // EMB*NH
#define NL 2
#define DENSE 128
#define QNPB 50         // nodes per qkvs/ftq/head block (50000 = 1000 * 50)
#define SBLK 49         // scan blocks: ceil(50000/1024)

// unpack two packed fp16 -> float2
__device__ __forceinline__ float2 h2f2(unsigned int u) {
    union { unsigned int u; _Float16 h[2]; } c; c.u = u;
    return make_float2((float)c.h[0], (float)c.h[1]);
}

// ---------------- CSR build ----------------
__global__ void hist_kernel(const int* __restrict__ dst, int* __restrict__ counts) {
    int e = blockIdx.x * blockDim.x + threadIdx.x;
    if (e < EE) atomicAdd(&counts[dst[e]], 1);
}

__global__ __launch_bounds__(1024) void scan1_kernel(const int* __restrict__ cursor,
                                                     int* __restrict__ row_ptr,
                                                     int* __restrict__ bsum) {
    __shared__ int wsum[16];
    __shared__ int wpre[17];
    int tid = threadIdx.x, lane = tid & 63, wid = tid >> 6;
    int i = blockIdx.x * 1024 + tid;
    int v = (i < NN) ? cursor[i] : 0;
    int incl = v;
    #pragma unroll
    for (int off = 1; off < 64; off <<= 1) {
        int t = __shfl_up(incl, off, 64);
        if (lane >= off) incl += t;
    }
    if (lane == 63) wsum[wid] = incl;
    __syncthreads();
    if (tid == 0) {
        int acc = 0;
        #pragma unroll
        for (int w = 0; w < 16; ++w) { wpre[w] = acc; acc += wsum[w]; }
        wpre[16] = acc;
    }
    __syncthreads();
    if (i < NN) row_ptr[i] = wpre[wid] + incl - v;
    if (tid == 0) bsum[blockIdx.x] = wpre[16];
}

__global__ void scan2_kernel(int* __restrict__ bsum, int* __restrict__ row_ptr) {
    int t = threadIdx.x;                               // 64 threads
    int v = (t < SBLK) ? bsum[t] : 0;
    int incl = v;
    #pragma unroll
    for (int off = 1; off < 64; off <<= 1) {
        int u = __shfl_up(incl, off, 64);
        if (t >= off) incl += u;
    }
    if (t < SBLK) bsum[t] = incl - v;
    if (t == 63) row_ptr[NN] = incl;
}

__global__ __launch_bounds__(1024) void scan3_kernel(int* __restrict__ row_ptr,
                                                     int* __restrict__ cursor,
                                                     const int* __restrict__ bsum) {
    int i = blockIdx.x * 1024 + threadIdx.x;
    if (i >= NN) return;
    int r = row_ptr[i] + bsum[blockIdx.x];
    row_ptr[i] = r;
    cursor[i] = r;
}

__global__ void scatter_kernel(const int* __restrict__ src, const int* __restrict__ dst,
                               const float* __restrict__ ea, int* __restrict__ cursor,
                               int* __restrict__ ssrc, float4* __restrict__ sea) {
    int e = blockIdx.x * blockDim.x + threadIdx.x;
    if (e >= EE) return;
    int d = dst[e];
    int pos = atomicAdd(&cursor[d], 1);
    ssrc[pos] = src[e];
    sea[pos] = *reinterpret_cast<const float4*>(ea + (size_t)e * 4);
}

// ---------------- layer-0 projections: Q f32, K/V packed fp16, skip into Out --------
__global__ __launch_bounds__(512) void qkvs0_kernel(const float* __restrict__ x,
        const float* __restrict__ Wq, const float* __restrict__ bq,
        const float* __restrict__ Wk, const float* __restrict__ bk,
        const float* __restrict__ Wv, const float* __restrict__ bv,
        const float* __restrict__ Ws, const float* __restrict__ bs,
        float* __restrict__ Q, _Float16* __restrict__ kvh,
        float* __restrict__ Out) {
    __shared__ float hs[QNPB][FIN];
    int tid = threadIdx.x;
    int m = tid >> 7, c = tid & 127;
    const float* W; const float* b;
    switch (m) {
        case 0:  W = Wq; b = bq; break;
        case 1:  W = Wk; b = bk; break;
        case 2:  W = Wv; b = bv; break;
        default: W = Ws; b = bs; break;
    }
    float w[FIN];
    #pragma unroll
    for (int f = 0; f < FIN; ++f) w[f] = W[f * HC + c];
    float bias = b[c];
    int node0 = blockIdx.x * QNPB;
    for (int i = tid; i < QNPB * FIN; i += 512)
        hs[i / FIN][i % FIN] = x[(size_t)node0 * FIN + i];
    __syncthreads();
    for (int k = 0; k < QNPB; ++k) {
        float s = bias;
        #pragma unroll
        for (int f = 0; f < FIN; ++f) s += hs[k][f] * w[f];
        size_t n = node0 + k;
        if      (m == 0) Q[n * HC + c] = s;
        else if (m == 1) kvh[n * 256 + 2 * c] = (_Float16)s;
        else if (m == 2) kvh[n * 256 + 2 * c + 1] = (_Float16)s;
        else             Out[n * HC + c] = s;
    }
}

// ---------- fused transform + projections: h = relu(Out@Wt+bt) (LDS), then QKVS ------
__global__ __launch_bounds__(512) void ftq_kernel(const float* __restrict__ Wt,
        const float* __restrict__ bt,
        const float* __restrict__ Wq, const float* __restrict__ bq,
        const float* __restrict__ Wk, const float* __restrict__ bk,
        const float* __restrict__ Wv, const float* __restrict__ bv,
        const float* __restrict__ Ws, const float* __restrict__ bs,
        float* __restrict__ Q, _Float16* __restrict__ kvh,
        float* __restrict__ Out) {
    __shared__ float os[QNPB * HC];     // 25.6 KB
    __shared__ float hs[QNPB][EMB];     // 6.4 KB
    int tid = threadIdx.x;
    int node0 = blockIdx.x * QNPB;
    for (int i = tid; i < QNPB * HC; i += 512)
        os[i] = Out[(size_t)node0 * HC + i];
    __syncthreads();
    for (int idx = tid; idx < QNPB * EMB; idx += 512) {
        int nl = idx >> 5, c = idx & 31;
        float s = bt[c];
        const float* r = os + nl * HC;
        #pragma unroll 8
        for (int j = 0; j < HC; ++j) s += r[j] * Wt[j * EMB + c];
        hs[nl][c] = fmaxf(s, 0.f);
    }
    __syncthreads();
    int m = tid >> 7, c = tid & 127;
    const float* W; const float* b;
    switch (m) {
        case 0:  W = Wq; b = bq; break;
        case 1:  W = Wk; b = bk; break;
        case 2:  W = Wv; b = bv; break;
        default: W = Ws; b = bs; break;
    }
    float w[EMB];
    #pragma unroll
    for (int f = 0; f < EMB; ++f) w[f] = W[f * HC + c];
    float bias = b[c];
    for (int k = 0; k < QNPB; ++k) {
        float s = bias;
        #pragma unroll
        for (int f = 0; f < EMB; ++f) s += hs[k][f] * w[f];
        size_t n = node0 + k;
        if      (m == 0) Q[n * HC + c] = s;
        else if (m == 1) kvh[n * 256 + 2 * c] = (_Float16)s;
        else if (m == 2) kvh[n * 256 + 2 * c + 1] = (_Float16)s;
        else             Out[n * HC + c] = s;
    }
}

// ------- edge attention: lane = channel pair, head = lane>>4, no-max softmax ---------
__global__ __launch_bounds__(256) void edge_attn_kernel(const int* __restrict__ row_ptr,
        const int* __restrict__ ssrc, const float4* __restrict__ sea,
        const float* __restrict__ We,
        const float* __restrict__ Q, const uint2* __restrict__ kvp,
        float2* __restrict__ Out) {
    int n = blockIdx.x * 4 + (threadIdx.x >> 6);   // grid*4 == NN exactly
    int lane = threadIdx.x & 63;
    int ch0 = 2 * lane, ch1 = 2 * lane + 1;
    float we0[4], we1[4];
    #pragma unroll
    for (int d = 0; d < 4; ++d) { we0[d] = We[d * HC + ch0]; we1[d] = We[d * HC + ch1]; }
    float2 q = ((const float2*)Q)[(size_t)n * 64 + lane];
    int start = row_ptr[n], end = row_ptr[n + 1];
    float z = 0.f, acc0 = 0.f, acc1 = 0.f;
    const float SC = 0.17677669529663687f;  // 1/sqrt(32)
    int i = start;
    for (; i + 1 < end; i += 2) {
        int sA = ssrc[i], sB = ssrc[i + 1];
        sA = sA < 0 ? 0 : (sA >= NN ? NN - 1 : sA);
        sB = sB < 0 ? 0 : (sB >= NN ? NN - 1 : sB);
        float4 eA = sea[i], eB = sea[i + 1];                     // wave-uniform
        uint2 kvA = kvp[(size_t)sA * 64 + lane];                 // k0,v0,k1,v1 fp16
        uint2 kvB = kvp[(size_t)sB * 64 + lane];
        float eA0 = eA.x * we0[0] + eA.y * we0[1] + eA.z * we0[2] + eA.w * we0[3];
        float eA1 = eA.x * we1[0] + eA.y * we1[1] + eA.z * we1[2] + eA.w * we1[3];
        float eB0 = eB.x * we0[0] + eB.y * we0[1] + eB.z * we0[2] + eB.w * we0[3];
        float eB1 = eB.x * we1[0] + eB.y * we1[1] + eB.z * we1[2] + eB.w * we1[3];
        float2 kvA0 = h2f2(kvA.x), kvA1 = h2f2(kvA.y);           // (k,v) ch0 / ch1
        float2 kvB0 = h2f2(kvB.x), kvB1 = h2f2(kvB.y);
        float pA = q.x * (kvA0.x + eA0) + q.y * (kvA1.x + eA1);
        float pB = q.x * (kvB0.x + eB0) + q.y * (kvB1.x + eB1);
        #pragma unroll
        for (int off = 1; off < 16; off <<= 1) {                 // 16-lane head groups
            pA += __shfl_xor(pA, off, 64);
            pB += __shfl_xor(pB, off, 64);
        }
        float xA = __expf(pA * SC), xB = __expf(pB * SC);
        z += xA + xB;
        acc0 += xA * (kvA0.y + eA0) + xB * (kvB0.y + eB0);
        acc1 += xA * (kvA1.y + eA1) + xB * (kvB1.y + eB1);
    }
    if (i < end) {
        int s = ssrc[i];
        s = s < 0 ? 0 : (s >= NN ? NN - 1 : s);
        float4 e = sea[i];
        uint2 kv = kvp[(size_t)s * 64 + lane];
        float e0 = e.x * we0[0] + e.y * we0[1] + e.z * we0[2] + e.w * we0[3];
        float e1 = e.x * we1[0] + e.y * we1[1] + e.z * we1[2] + e.w * we1[3];
        float2 kv0 = h2f2(kv.x), kv1 = h2f2(kv.y);
        float p = q.x * (kv0.x + e0) + q.y * (kv1.x + e1);
        #pragma unroll
        for (int off = 1; off < 16; off <<= 1) p += __shfl_xor(p, off, 64);
        float x = __expf(p * SC);
        z += x;
        acc0 += x * (kv0.y + e0);
        acc1 += x * (kv1.y + e1);
    }
    float inv = 1.f / (z + 1e-16f);
    size_t oi = (size_t)n * 64 + lane;
    float2 o = Out[oi];
    o.x += acc0 * inv;
    o.y += acc1 * inv;
    Out[oi] = o;
}

// ---- fused final transform + MLP head, register-cached weights, 50 nodes/block ------
__global__ __launch_bounds__(512) void head2_kernel(const float* __restrict__ Outb,
        const float* __restrict__ Wt, const float* __restrict__ bt,
        const float* __restrict__ W1, const float* __restrict__ b1,
        const float* __restrict__ W2, const float* __restrict__ b2,
        const float* __restrict__ W3, const float* __restrict__ b3,
        float* __restrict__ out) {
    __shared__ float os[QNPB * HC];      // 25.6 KB; reused as d1s after stage T
    __shared__ float hs[QNPB * EMB];     // 6.4 KB
    __shared__ float d2s[QNPB * 64];     // 12.8 KB
    float* d1s = os;                     // alias: os dead once hs is built
    int tid = threadIdx.x;
    int node0 = blockIdx.x * QNPB;
    int g = tid >> 7;                    // 4 node-groups (2 waves each)

    // stage 0: stage Outb rows
    for (int i = tid; i < QNPB * HC; i += 512)
        os[i] = Outb[(size_t)node0 * HC + i];

    // stage T: h = relu(bt + Outb @ Wt). thread (g, cT=(tid&127)>>2, seg=tid&3)
    int cT = (tid & 127) >> 2, seg = tid & 3;
    float wt[32];
    #pragma unroll
    for (int j = 0; j < 32; ++j) wt[j] = Wt[(seg * 32 + j) * EMB + cT];
    float btc = bt[cT];
    __syncthreads();
    for (int k = g; k < QNPB; k += 4) {
        float p = 0.f;
        const float* r = os + k * HC + seg * 32;
        #pragma unroll
        for (int j = 0; j < 32; ++j) p += r[j] * wt[j];
        p += __shfl_xor(p, 1, 64);       // seg pairs
        p += __shfl_xor(p, 2, 64);
        if (seg == 0) hs[k * EMB + cT] = fmaxf(p + btc, 0.f);
    }
    __syncthreads();                     // hs ready; os now dead -> d1s

    // stage 1: d1 = relu(b1 + h @ W1). thread (g, c1=tid&127), 32-reg column
    int c1 = tid & 127;
    float w1[32];
    #pragma unroll
    for (int f = 0; f < 32; ++f) w1[f] = W1[f * DENSE + c1];
    float b1c = b1[c1];
    for (int k = g; k < QNPB; k += 4) {
        float s = b1c;
        #pragma unroll
        for (int f = 0; f < 32; ++f) s += hs[k * EMB + f] * w1[f];
        d1s[k * DENSE + c1] = fmaxf(s, 0.f);
    }
    __syncthreads();                     // d1s ready

    // stage 2: d2 = relu(b2 + d1 @ W2). thread (g, c2=(tid&127)>>1, h=tid&1), 64 regs
    int c2 = (tid & 127) >> 1, hh = tid & 1;
    float w2[64];
    #pragma unroll
    for (int j = 0; j < 64; ++j) w2[j] = W2[(hh * 64 + j) * 64 + c2];
    float b2c = b2[c2];
    for (int k = g; k < QNPB; k += 4) {
        float p = 0.f;
        const float* r = d1s + k * DENSE + hh * 64;
        #pragma unroll
        for (int j = 0; j < 64; ++j) p += r[j] * w2[j];
        p += __shfl_xor(p, 1, 64);       // halves
        if (hh == 0) d2s[k * 64 + c2] = fmaxf(p + b2c, 0.f);
    }
    __syncthreads();

    // stage 3: out = sigmoid(b3 + d2 @ W3). wave per node
    int w = tid >> 6, lane = tid & 63;
    float w3r = W3[lane];
    float b3r = b3[0];
    for (int k = w; k < QNPB; k += 8) {
        float t = d2s[k * 64 + lane] * w3r;
        #pragma unroll
        for (int off = 1; off < 64; off <<= 1) t += __shfl_xor(t, off, 64);
        if (lane == 0) out[node0 + k] = 1.f / (1.f + __expf(-(t + b3r)));
    }
}

extern "C" void kernel_launch(void* const* d_in, const int* in_sizes, int n_in,
                              void* d_out, int out_size, void* d_ws, size_t ws_size,
                              hipStream_t stream) {
    const float* x   = (const float*)d_in[0];
    const int*   ei  = (const int*)d_in[1];    // [2,E]: src=ei, dst=ei+E
    const float* ea  = (const float*)d_in[2];
    const float* Wq0 = (const float*)d_in[3];  const float* bq0 = (const float*)d_in[4];
    const float* Wk0 = (const float*)d_in[5];  const float* bk0 = (const float*)d_in[6];
    const float* Wv0 = (const float*)d_in[7];  const float* bv0 = (const float*)d_in[8];
    const float* We0 = (const float*)d_in[9];
    const float* Ws0 = (const float*)d_in[10]; const float* bs0 = (const float*)d_in[11];
    const float* Wt0 = (const float*)d_in[12]; const float* bt0 = (const float*)d_in[13];
    const float* WqL = (const float*)d_in[14]; const float* bqL = (const float*)d_in[15];
    const float* WkL = (const float*)d_in[16]; const float* bkL = (const float*)d_in[17];
    const float* WvL = (const float*)d_in[18]; const float* bvL = (const float*)d_in[19];
    const float* WeL = (const float*)d_in[20];
    const float* WsL = (const float*)d_in[21]; const float* bsL = (const float*)d_in[22];
    const float* WtL = (const float*)d_in[23]; const float* btL = (const float*)d_in[24];
    const float* W1  = (const float*)d_in[25]; const float* b1  = (const float*)d_in[26];
    const float* W2  = (const float*)d_in[27]; const float* b2  = (const float*)d_in[28];
    const float* W3  = (const float*)d_in[29]; const float* b3  = (const float*)d_in[30];
    float* out = (float*)d_out;

    char* ws = (char*)d_ws;
    size_t off = 0;
    auto alloc = [&](size_t bytes) -> void* {
        void* p = ws + off; off = (off + bytes + 255) & ~(size_t)255; return p;
    };
    int*     cursor  = (int*)    alloc((size_t)NN * 4);
    int*     row_ptr = (int*)    alloc((size_t)(NN + 1) * 4);
    int*     bsum    = (int*)    alloc((size_t)SBLK * 4);
    int*     ssrc    = (int*)    alloc((size_t)EE * 4);
    float4*  sea     = (float4*) alloc((size_t)EE * 16);
    float*   Q       = (float*)  alloc((size_t)NN * HC * 4);
    _Float16* kvh    = (_Float16*)alloc((size_t)NN * HC * 2 * 2);  // (k,v) interleaved
    float*   Outb    = (float*)  alloc((size_t)NN * HC * 4);
    // total ~93 MB

    // ---- CSR by dst (edge_index shared by all 3 conv layers) ----
    hipMemsetAsync(cursor, 0, (size_t)NN * 4, stream);
    hist_kernel<<<(EE + 255) / 256, 256, 0, stream>>>(ei + EE, cursor);
    scan1_kernel<<<SBLK, 1024, 0, stream>>>(cursor, row_ptr, bsum);
    scan2_kernel<<<1, 64, 0, stream>>>(bsum, row_ptr);
    scan3_kernel<<<SBLK, 1024, 0, stream>>>(row_ptr, cursor, bsum);
    scatter_kernel<<<(EE + 255) / 256, 256, 0, stream>>>(ei, ei + EE, ea, cursor, ssrc, sea);

    const uint2* kvp = (const uint2*)kvh;
    float2* Out2 = (float2*)Outb;

    // ---- layer 0 ----
    qkvs0_kernel<<<NN / QNPB, 512, 0, stream>>>(x, Wq0, bq0, Wk0, bk0, Wv0, bv0,
                                                Ws0, bs0, Q, kvh, Outb);
    edge_attn_kernel<<<NN / 4, 256, 0, stream>>>(row_ptr, ssrc, sea, We0, Q, kvp, Out2);

    // ---- layer 1: fused transform(Wt0) + projections(WqL[0]) ----
    ftq_kernel<<<NN / QNPB, 512, 0, stream>>>(Wt0, bt0,
        WqL, bqL, WkL, bkL, WvL, bvL, WsL, bsL, Q, kvh, Outb);
    edge_attn_kernel<<<NN / 4, 256, 0, stream>>>(row_ptr, ssrc, sea, WeL, Q, kvp, Out2);

    // ---- layer 2: fused transform(Wt[0]) + projections(WqL[1]) ----
    ftq_kernel<<<NN / QNPB, 512, 0, stream>>>(WtL, btL,
        WqL + EMB * HC, bqL + HC, WkL + EMB * HC, bkL + HC,
        WvL + EMB * HC, bvL + HC, WsL + EMB * HC, bsL + HC, Q, kvh, Outb);
    edge_attn_kernel<<<NN / 4, 256, 0, stream>>>(row_ptr, ssrc, sea,
        WeL + EDIM * HC, Q, kvp, Out2);

    // ---- fused final transform(Wt[1]) + register-weight MLP head ----
    head2_kernel<<<NN / QNPB, 512, 0, stream>>>(Outb, WtL + (size_t)HC * EMB, btL + EMB,
                                                W1, b1, W2, b2, W3, b3, out);
}